// Round 1
// baseline (450.689 us; speedup 1.0000x reference)
//
#include <hip/hip_runtime.h>
#include <stdint.h>

typedef __attribute__((ext_vector_type(8))) short bf16x8;
typedef __attribute__((ext_vector_type(4))) float f32x4;
typedef __attribute__((ext_vector_type(2))) unsigned int u32x2;
typedef unsigned short u16;
typedef unsigned int u32;

#define MFMA16(a, b, c) __builtin_amdgcn_mfma_f32_16x16x32_bf16((a), (b), (c), 0, 0, 0)

__device__ __forceinline__ u16 f2bf(float f) {
  union { float f; u32 u; } c; c.f = f;
  u32 u = c.u;
  return (u16)((u + 0x7FFFu + ((u >> 16) & 1u)) >> 16);
}

__device__ __forceinline__ void gll16(const void* g, void* l) {
  __builtin_amdgcn_global_load_lds((__attribute__((address_space(1))) void*)(g),
                                   (__attribute__((address_space(3))) void*)(l),
                                   16, 0, 0);
}

// ---------------- prep: cast x to bf16 ----------------
__global__ __launch_bounds__(256) void cast_k(const float* __restrict__ x, u16* __restrict__ xb) {
  int idx = blockIdx.x * 256 + threadIdx.x;
#pragma unroll
  for (int it = 0; it < 4; it++) {
    size_t i = (size_t)idx + (size_t)it * 1048576;
    float4 v = ((const float4*)x)[i];
    u32x2 p;
    p.x = (u32)f2bf(v.x) | ((u32)f2bf(v.y) << 16);
    p.y = (u32)f2bf(v.z) | ((u32)f2bf(v.w) << 16);
    ((u32x2*)xb)[i] = p;
  }
}

// ---------------- prep: weight transpose to [N][K] bf16 ----------------
__global__ __launch_bounds__(256) void wT_k(const float* __restrict__ Wq, const float* __restrict__ Wk,
                                            const float* __restrict__ Wv, const float* __restrict__ Wo,
                                            u16* __restrict__ wqkvT, u16* __restrict__ woT) {
  __shared__ float t[32][33];
  int which = blockIdx.z;
  const float* W = (which == 0) ? Wq : (which == 1) ? Wk : (which == 2) ? Wv : Wo;
  int k0 = blockIdx.y * 32, n0 = blockIdx.x * 32;
  int c = threadIdx.x & 31, r8 = threadIdx.x >> 5;
#pragma unroll
  for (int rr = 0; rr < 32; rr += 8)
    t[r8 + rr][c] = W[(size_t)(k0 + r8 + rr) * 1024 + n0 + c];
  __syncthreads();
  u16* outp = (which < 3) ? (wqkvT + (size_t)which * 1048576) : woT;
#pragma unroll
  for (int rr = 0; rr < 32; rr += 8)
    outp[(size_t)(n0 + r8 + rr) * 1024 + k0 + c] = f2bf(t[c][r8 + rr]);
}

// ---------------- GEMM (m97 structure): C = A[M,K] * Bt[N,K]^T ----------------
// MODE 0: QKV (N=3072): epilogue bias + phi for q,k; scatter to [B,H,L,D] bf16
// MODE 1: OUT (N=1024): epilogue + bo + residual x, write f32 ypre
template <int MODE>
__global__ __launch_bounds__(256, 2) void gemm_k(
    const u16* __restrict__ A, const u16* __restrict__ Bt,
    const float* __restrict__ b0, const float* __restrict__ b1, const float* __restrict__ b2,
    u16* __restrict__ q_o, u16* __restrict__ k_o, u16* __restrict__ v_o,
    const float* __restrict__ xres, float* __restrict__ y_o) {
  __shared__ u16 As[128 * 32];
  __shared__ u16 Bs[128 * 32];
  const int tid = threadIdx.x;
  const int wave = tid >> 6, lane = tid & 63;
  const int quad = lane >> 4, l16 = lane & 15;
  const int wr = wave >> 1, wc = wave & 1;
  const int bn = blockIdx.x, bm = blockIdx.y;

  const int r_a = wave * 32 + (lane >> 2);
  const int c_a = (lane & 3) * 8;
  const size_t arow = (size_t)bm * 128;
  const size_t brow = (size_t)bn * 128;

  f32x4 zero = {0.f, 0.f, 0.f, 0.f};
  f32x4 acc[4][4];
#pragma unroll
  for (int i = 0; i < 4; i++)
#pragma unroll
    for (int j = 0; j < 4; j++) acc[i][j] = zero;

  for (int k0 = 0; k0 < 1024; k0 += 32) {
#pragma unroll
    for (int jc = 0; jc < 2; jc++) {
      int r = r_a + jc * 16;
      int lo = wave * 1024 + jc * 512 + lane * 8;
      gll16(A + (arow + r) * 1024 + k0 + c_a, &As[lo]);
      gll16(Bt + (brow + r) * 1024 + k0 + c_a, &Bs[lo]);
    }
    __syncthreads();
    bf16x8 af[4], bf[4];
#pragma unroll
    for (int t = 0; t < 4; t++) af[t] = *(const bf16x8*)&As[(wr * 64 + t * 16 + l16) * 32 + quad * 8];
#pragma unroll
    for (int t = 0; t < 4; t++) bf[t] = *(const bf16x8*)&Bs[(wc * 64 + t * 16 + l16) * 32 + quad * 8];
#pragma unroll
    for (int i = 0; i < 4; i++)
#pragma unroll
      for (int j = 0; j < 4; j++) acc[i][j] = MFMA16(af[i], bf[j], acc[i][j]);
    __syncthreads();
  }

#pragma unroll
  for (int i = 0; i < 4; i++) {
#pragma unroll
    for (int j = 0; j < 4; j++) {
#pragma unroll
      for (int r = 0; r < 4; r++) {
        int m_g = bm * 128 + wr * 64 + i * 16 + quad * 4 + r;
        int n_g = bn * 128 + wc * 64 + j * 16 + l16;
        float v = acc[i][j][r];
        if (MODE == 0) {
          int sec = n_g >> 10;
          int e = n_g & 1023;
          const float* bias = (sec == 0) ? b0 : ((sec == 1) ? b1 : b2);
          v += bias[e];
          if (sec < 2) v = (v > 0.f) ? (v + 1.f) : __expf(v);
          int h = e >> 6, d = e & 63;
          int b = m_g >> 13, l = m_g & 8191;
          u16* dst = (sec == 0) ? q_o : ((sec == 1) ? k_o : v_o);
          dst[((((size_t)(b * 16 + h)) * 8192 + l) << 6) + d] = f2bf(v);
        } else {
          v += b0[n_g] + xres[(size_t)m_g * 1024 + n_g];
          y_o[(size_t)m_g * 1024 + n_g] = v;
        }
      }
    }
  }
}

// ---------------- phase A: per-chunk S^T = v^T k (stored [d2][d1]) and z = sum_c k ----------------
__global__ __launch_bounds__(256, 2) void phaseA_k(const u16* __restrict__ kb, const u16* __restrict__ vb,
                                                   float* __restrict__ ST, float* __restrict__ zc) {
  __shared__ u16 kT[64 * 72];
  __shared__ u16 vT[64 * 72];
  const int tid = threadIdx.x;
  const int wave = tid >> 6, lane = tid & 63;
  const int quad = lane >> 4, l16 = lane & 15;
  const int wr = wave >> 1, wc = wave & 1;
  const int bhn = blockIdx.x;
  const size_t cbase = (size_t)bhn * 16384;
  const u16* kc = kb + cbase;
  const u16* vc = vb + cbase;

  f32x4 zero = {0.f, 0.f, 0.f, 0.f};
  f32x4 t4[2][2];
  f32x4 za[2];
#pragma unroll
  for (int i = 0; i < 2; i++) {
    za[i] = zero;
#pragma unroll
    for (int j = 0; j < 2; j++) t4[i][j] = zero;
  }
  bf16x8 ones;
#pragma unroll
  for (int j = 0; j < 8; j++) ones[j] = (short)0x3F80;

  for (int sc = 0; sc < 4; sc++) {
#pragma unroll
    for (int it = 0; it < 2; it++) {
      int idx = tid + 256 * it;
      int c = idx >> 3, dblk = idx & 7;
      bf16x8 kv = *(const bf16x8*)&kc[(sc * 64 + c) * 64 + dblk * 8];
      bf16x8 vv = *(const bf16x8*)&vc[(sc * 64 + c) * 64 + dblk * 8];
#pragma unroll
      for (int j = 0; j < 8; j++) {
        kT[(dblk * 8 + j) * 72 + c] = (u16)kv[j];
        vT[(dblk * 8 + j) * 72 + c] = (u16)vv[j];
      }
    }
    __syncthreads();
#pragma unroll
    for (int ks = 0; ks < 2; ks++) {
      bf16x8 av[2], bk2[2];
#pragma unroll
      for (int t = 0; t < 2; t++) av[t] = *(const bf16x8*)&vT[(wr * 32 + t * 16 + l16) * 72 + ks * 32 + quad * 8];
#pragma unroll
      for (int t = 0; t < 2; t++) bk2[t] = *(const bf16x8*)&kT[(wc * 32 + t * 16 + l16) * 72 + ks * 32 + quad * 8];
#pragma unroll
      for (int i = 0; i < 2; i++)
#pragma unroll
        for (int j = 0; j < 2; j++) t4[i][j] = MFMA16(av[i], bk2[j], t4[i][j]);
      if (wr == 0) {
#pragma unroll
        for (int j = 0; j < 2; j++) za[j] = MFMA16(ones, bk2[j], za[j]);
      }
    }
    __syncthreads();
  }
  float* Sg = ST + (size_t)bhn * 4096;
#pragma unroll
  for (int i = 0; i < 2; i++)
#pragma unroll
    for (int j = 0; j < 2; j++)
#pragma unroll
      for (int r = 0; r < 4; r++)
        Sg[(wr * 32 + i * 16 + quad * 4 + r) * 64 + wc * 32 + j * 16 + l16] = t4[i][j][r];
  if (wr == 0 && quad == 0) {
#pragma unroll
    for (int j = 0; j < 2; j++) zc[(size_t)bhn * 64 + wc * 32 + j * 16 + l16] = za[j][0];
  }
}

// ---------------- phase B: exclusive prefix over chunks ----------------
__global__ __launch_bounds__(256) void phaseB_k(const float* __restrict__ ST, const float* __restrict__ zc,
                                                u16* __restrict__ STp, u16* __restrict__ zp) {
  int bh = blockIdx.x, tid = threadIdx.x;
  float run[16];
#pragma unroll
  for (int i = 0; i < 16; i++) run[i] = 0.f;
  float runz = 0.f;
  for (int n = 0; n < 32; n++) {
    size_t base = ((size_t)bh * 32 + n) * 4096;
#pragma unroll
    for (int i = 0; i < 16; i++) {
      size_t e = base + tid + 256 * i;
      STp[e] = f2bf(run[i]);
      run[i] += ST[e];
    }
    if (tid < 64) {
      size_t zb = ((size_t)bh * 32 + n) * 64 + tid;
      zp[zb] = f2bf(runz);
      runz += zc[zb];
    }
  }
}

// ---------------- phase C: per-chunk output ----------------
__global__ __launch_bounds__(256, 2) void phaseC_k(const u16* __restrict__ qb, const u16* __restrict__ kb,
                                                   const u16* __restrict__ vb, const u16* __restrict__ STp,
                                                   const u16* __restrict__ zp, u16* __restrict__ ao) {
  __shared__ u16 vT[64 * 136];
  __shared__ u16 P[4][64 * 72];
  const int tid = threadIdx.x;
  const int wave = tid >> 6, lane = tid & 63;
  const int quad = lane >> 4, l16 = lane & 15;
  const int bhn = blockIdx.x;
  const int bh = bhn >> 5, n = bhn & 31;
  const int b = bh >> 4, h = bh & 15;
  const size_t cbase = (size_t)bhn * 16384;
  const u16* qc = qb + cbase;
  const u16* kc = kb + cbase;
  const u16* vc = vb + cbase;
  const u16* STg = STp + (size_t)bhn * 4096;
  const u16* zg = zp + (size_t)bhn * 64;

  f32x4 zero = {0.f, 0.f, 0.f, 0.f};
  f32x4 num[4][4];
  f32x4 den[4];
#pragma unroll
  for (int i = 0; i < 4; i++) {
    den[i] = zero;
#pragma unroll
    for (int j = 0; j < 4; j++) num[i][j] = zero;
  }
  bf16x8 ones;
#pragma unroll
  for (int j = 0; j < 8; j++) ones[j] = (short)0x3F80;

  // preload q fragments for this wave's 64-row band
  bf16x8 aq[4][2];
#pragma unroll
  for (int i = 0; i < 4; i++)
#pragma unroll
    for (int ks = 0; ks < 2; ks++)
      aq[i][ks] = *(const bf16x8*)&qc[(wave * 64 + i * 16 + l16) * 64 + ks * 32 + quad * 8];

  // num += q @ S_prefix ; den += q . z_prefix (z replicated across B cols)
#pragma unroll
  for (int ks = 0; ks < 2; ks++) {
    bf16x8 bz = *(const bf16x8*)&zg[ks * 32 + quad * 8];
    bf16x8 bs[4];
#pragma unroll
    for (int j = 0; j < 4; j++) bs[j] = *(const bf16x8*)&STg[(j * 16 + l16) * 64 + ks * 32 + quad * 8];
#pragma unroll
    for (int i = 0; i < 4; i++) {
      den[i] = MFMA16(aq[i][ks], bz, den[i]);
#pragma unroll
      for (int j = 0; j < 4; j++) num[i][j] = MFMA16(aq[i][ks], bs[j], num[i][j]);
    }
  }

  u16* Pw = &P[wave][0];

  for (int cc = 0; cc < 4; cc++) {
    if ((cc & 1) == 0) {
      // stage v^T for columns [cc*64, cc*64+128)
#pragma unroll
      for (int it = 0; it < 4; it++) {
        int idx = tid + 256 * it;
        int cl = idx >> 3, dblk = idx & 7;
        bf16x8 vv = *(const bf16x8*)&vc[(cc * 64 + cl) * 64 + dblk * 8];
#pragma unroll
        for (int j = 0; j < 8; j++) vT[(dblk * 8 + j) * 136 + cl] = (u16)vv[j];
      }
      __syncthreads();
    }
    // scores = q k^T for this 64-col slab, mask, write P (bf16, per-wave region)
    bf16x8 bkf[2][4];
#pragma unroll
    for (int ks = 0; ks < 2; ks++)
#pragma unroll
      for (int j = 0; j < 4; j++)
        bkf[ks][j] = *(const bf16x8*)&kc[(cc * 64 + j * 16 + l16) * 64 + ks * 32 + quad * 8];
#pragma unroll
    for (int i = 0; i < 4; i++) {
      f32x4 sc4[4];
#pragma unroll
      for (int j = 0; j < 4; j++) sc4[j] = zero;
#pragma unroll
      for (int ks = 0; ks < 2; ks++)
#pragma unroll
        for (int j = 0; j < 4; j++) sc4[j] = MFMA16(aq[i][ks], bkf[ks][j], sc4[j]);
#pragma unroll
      for (int j = 0; j < 4; j++) {
#pragma unroll
        for (int r = 0; r < 4; r++) {
          int row = wave * 64 + i * 16 + quad * 4 + r;
          int col = cc * 64 + j * 16 + l16;
          float v = (col <= row) ? sc4[j][r] : 0.f;
          Pw[(i * 16 + quad * 4 + r) * 72 + j * 16 + l16] = f2bf(v);
        }
      }
    }
    __syncthreads();
    // num += P @ v ; den += rowsum(P) via ones fragment
    bf16x8 bvf[2][4];
#pragma unroll
    for (int ks2 = 0; ks2 < 2; ks2++)
#pragma unroll
      for (int j = 0; j < 4; j++)
        bvf[ks2][j] = *(const bf16x8*)&vT[(j * 16 + l16) * 136 + (cc & 1) * 64 + ks2 * 32 + quad * 8];
#pragma unroll
    for (int i = 0; i < 4; i++) {
#pragma unroll
      for (int ks2 = 0; ks2 < 2; ks2++) {
        bf16x8 ap = *(const bf16x8*)&Pw[(i * 16 + l16) * 72 + ks2 * 32 + quad * 8];
#pragma unroll
        for (int j = 0; j < 4; j++) num[i][j] = MFMA16(ap, bvf[ks2][j], num[i][j]);
        den[i] = MFMA16(ap, ones, den[i]);
      }
    }
    __syncthreads();
  }

  // epilogue: divide and scatter to attnout [B,L,H,D] bf16
#pragma unroll
  for (int i = 0; i < 4; i++)
#pragma unroll
    for (int j = 0; j < 4; j++)
#pragma unroll
      for (int r = 0; r < 4; r++) {
        int row = wave * 64 + i * 16 + quad * 4 + r;
        int col = j * 16 + l16;
        float o = num[i][j][r] / (den[i][r] + 1e-6f);
        int l = n * 256 + row;
        ao[(((size_t)b * 8192 + l) * 16 + h) * 64 + col] = f2bf(o);
      }
}

// ---------------- LayerNorm ----------------
__global__ __launch_bounds__(256) void ln_k(const float* __restrict__ y, const float* __restrict__ gamma,
                                            const float* __restrict__ beta, float* __restrict__ o) {
  int row = blockIdx.x, tid = threadIdx.x;
  const float4* yv = (const float4*)(y + (size_t)row * 1024);
  float4 v = yv[tid];
  float s = v.x + v.y + v.z + v.w;
  float s2 = v.x * v.x + v.y * v.y + v.z * v.z + v.w * v.w;
#pragma unroll
  for (int off = 32; off; off >>= 1) {
    s += __shfl_down(s, off, 64);
    s2 += __shfl_down(s2, off, 64);
  }
  __shared__ float red[8];
  int wave = tid >> 6, lane = tid & 63;
  if (lane == 0) { red[wave] = s; red[4 + wave] = s2; }
  __syncthreads();
  s = red[0] + red[1] + red[2] + red[3];
  s2 = red[4] + red[5] + red[6] + red[7];
  float mu = s * 0.0009765625f;
  float var = s2 * 0.0009765625f - mu * mu;
  float inv = rsqrtf(var + 1e-5f);
  float4 g = ((const float4*)gamma)[tid];
  float4 bb = ((const float4*)beta)[tid];
  float4 ov;
  ov.x = g.x * (v.x - mu) * inv + bb.x;
  ov.y = g.y * (v.y - mu) * inv + bb.y;
  ov.z = g.z * (v.z - mu) * inv + bb.z;
  ov.w = g.w * (v.w - mu) * inv + bb.w;
  ((float4*)(o + (size_t)row * 1024))[tid] = ov;
}

extern "C" void kernel_launch(void* const* d_in, const int* in_sizes, int n_in,
                              void* d_out, int out_size, void* d_ws, size_t ws_size,
                              hipStream_t stream) {
  const float* x = (const float*)d_in[0];
  const float* Wq = (const float*)d_in[1];
  const float* bq = (const float*)d_in[2];
  const float* Wk = (const float*)d_in[3];
  const float* bk = (const float*)d_in[4];
  const float* Wv = (const float*)d_in[5];
  const float* bv = (const float*)d_in[6];
  const float* Wo = (const float*)d_in[7];
  const float* bo = (const float*)d_in[8];
  const float* gamma = (const float*)d_in[9];
  const float* beta = (const float*)d_in[10];

  char* ws = (char*)d_ws;
  u16* xb = (u16*)(ws + 0);                  // 33554432 B
  u16* qb = (u16*)(ws + 33554432);           // 33554432 B
  u16* kb = (u16*)(ws + 67108864);           // 33554432 B
  u16* vb = (u16*)(ws + 100663296);          // 33554432 B
  u16* wqkvT = (u16*)(ws + 134217728);       // 6291456 B
  u16* woT = (u16*)(ws + 140509184);         // 2097152 B
  float* SchT = (float*)(ws + 142606336);    // 16777216 B
  float* zch = (float*)(ws + 159383552);     // 262144 B
  u16* STp = (u16*)(ws + 159645696);         // 8388608 B
  u16* zp = (u16*)(ws + 168034304);          // 131072 B
  u16* attno = (u16*)(ws + 168165376);       // 33554432 B
  float* ypre = (float*)(ws + 0);            // 67108864 B, aliases xb+qb (dead by then)

  cast_k<<<4096, 256, 0, stream>>>(x, xb);
  wT_k<<<dim3(32, 32, 4), 256, 0, stream>>>(Wq, Wk, Wv, Wo, wqkvT, woT);
  gemm_k<0><<<dim3(24, 128), 256, 0, stream>>>(xb, wqkvT, bq, bk, bv, qb, kb, vb, nullptr, nullptr);
  phaseA_k<<<1024, 256, 0, stream>>>(kb, vb, SchT, zch);
  phaseB_k<<<32, 256, 0, stream>>>(SchT, zch, STp, zp);
  phaseC_k<<<1024, 256, 0, stream>>>(qb, kb, vb, STp, zp, attno);
  gemm_k<1><<<dim3(8, 128), 256, 0, stream>>>(attno, woT, bo, nullptr, nullptr, nullptr, nullptr, nullptr, x,
                                              ypre);
  ln_k<<<16384, 256, 0, stream>>>(ypre, gamma, beta, (float*)d_out);
}

// Round 3
// 438.857 us; speedup vs baseline: 1.0270x; 1.0270x over previous
//
#include <hip/hip_runtime.h>
#include <stdint.h>

typedef __attribute__((ext_vector_type(8))) short bf16x8;
typedef __attribute__((ext_vector_type(4))) float f32x4;
typedef __attribute__((ext_vector_type(2))) unsigned int u32x2;
typedef unsigned short u16;
typedef unsigned int u32;

#define MFMA16(a, b, c) __builtin_amdgcn_mfma_f32_16x16x32_bf16((a), (b), (c), 0, 0, 0)

__device__ __forceinline__ u16 f2bf(float f) {
  union { float f; u32 u; } c; c.f = f;
  u32 u = c.u;
  return (u16)((u + 0x7FFFu + ((u >> 16) & 1u)) >> 16);
}

__device__ __forceinline__ void gll16(const void* g, void* l) {
  __builtin_amdgcn_global_load_lds((__attribute__((address_space(1))) void*)(g),
                                   (__attribute__((address_space(3))) void*)(l),
                                   16, 0, 0);
}

// ---------------- prep: cast x to bf16 ----------------
__global__ __launch_bounds__(256) void cast_k(const float* __restrict__ x, u16* __restrict__ xb) {
  int idx = blockIdx.x * 256 + threadIdx.x;
#pragma unroll
  for (int it = 0; it < 4; it++) {
    size_t i = (size_t)idx + (size_t)it * 1048576;
    float4 v = ((const float4*)x)[i];
    u32x2 p;
    p.x = (u32)f2bf(v.x) | ((u32)f2bf(v.y) << 16);
    p.y = (u32)f2bf(v.z) | ((u32)f2bf(v.w) << 16);
    ((u32x2*)xb)[i] = p;
  }
}

// ---------------- prep: weight transpose to [N][K] bf16 ----------------
__global__ __launch_bounds__(256) void wT_k(const float* __restrict__ Wq, const float* __restrict__ Wk,
                                            const float* __restrict__ Wv, const float* __restrict__ Wo,
                                            u16* __restrict__ wqkvT, u16* __restrict__ woT) {
  __shared__ float t[32][33];
  int which = blockIdx.z;
  const float* W = (which == 0) ? Wq : (which == 1) ? Wk : (which == 2) ? Wv : Wo;
  int k0 = blockIdx.y * 32, n0 = blockIdx.x * 32;
  int c = threadIdx.x & 31, r8 = threadIdx.x >> 5;
#pragma unroll
  for (int rr = 0; rr < 32; rr += 8)
    t[r8 + rr][c] = W[(size_t)(k0 + r8 + rr) * 1024 + n0 + c];
  __syncthreads();
  u16* outp = (which < 3) ? (wqkvT + (size_t)which * 1048576) : woT;
#pragma unroll
  for (int rr = 0; rr < 32; rr += 8)
    outp[(size_t)(n0 + r8 + rr) * 1024 + k0 + c] = f2bf(t[c][r8 + rr]);
}

// ---------------- GEMM (m97 structure): C = A[M,K] * Bt[N,K]^T ----------------
// MODE 0: QKV (N=3072): bias + phi(q,k); writes q,k natural [B,H,L,D] and kt,vt
//         transposed [B,H,N,D,C] (per-chunk [d][c], 8B packed stores).
// MODE 1: OUT (N=1024): + bo + residual x, write f32 ypre
template <int MODE>
__global__ __launch_bounds__(256, 2) void gemm_k(
    const u16* __restrict__ A, const u16* __restrict__ Bt,
    const float* __restrict__ b0, const float* __restrict__ b1, const float* __restrict__ b2,
    u16* __restrict__ q_o, u16* __restrict__ k_o, u16* __restrict__ kt_o, u16* __restrict__ vt_o,
    const float* __restrict__ xres, float* __restrict__ y_o) {
  __shared__ u16 As[128 * 32];
  __shared__ u16 Bs[128 * 32];
  const int tid = threadIdx.x;
  const int wave = tid >> 6, lane = tid & 63;
  const int quad = lane >> 4, l16 = lane & 15;
  const int wr = wave >> 1, wc = wave & 1;
  const int bn = blockIdx.x, bm = blockIdx.y;

  const int r_a = wave * 32 + (lane >> 2);
  const int c_a = (lane & 3) * 8;
  const size_t arow = (size_t)bm * 128;
  const size_t brow = (size_t)bn * 128;

  f32x4 zero = {0.f, 0.f, 0.f, 0.f};
  f32x4 acc[4][4];
#pragma unroll
  for (int i = 0; i < 4; i++)
#pragma unroll
    for (int j = 0; j < 4; j++) acc[i][j] = zero;

  for (int k0 = 0; k0 < 1024; k0 += 32) {
#pragma unroll
    for (int jc = 0; jc < 2; jc++) {
      int r = r_a + jc * 16;
      int lo = wave * 1024 + jc * 512 + lane * 8;
      gll16(A + (arow + r) * 1024 + k0 + c_a, &As[lo]);
      gll16(Bt + (brow + r) * 1024 + k0 + c_a, &Bs[lo]);
    }
    __syncthreads();
    bf16x8 af[4], bf[4];
#pragma unroll
    for (int t = 0; t < 4; t++) af[t] = *(const bf16x8*)&As[(wr * 64 + t * 16 + l16) * 32 + quad * 8];
#pragma unroll
    for (int t = 0; t < 4; t++) bf[t] = *(const bf16x8*)&Bs[(wc * 64 + t * 16 + l16) * 32 + quad * 8];
#pragma unroll
    for (int i = 0; i < 4; i++)
#pragma unroll
      for (int j = 0; j < 4; j++) acc[i][j] = MFMA16(af[i], bf[j], acc[i][j]);
    __syncthreads();
  }

  if (MODE == 0) {
#pragma unroll
    for (int i = 0; i < 4; i++) {
      const int m0 = bm * 128 + wr * 64 + i * 16 + quad * 4;  // 4 consecutive tokens
      const int b = m0 >> 13, l0 = m0 & 8191;
      const int nch = l0 >> 8, c0 = l0 & 255;
#pragma unroll
      for (int j = 0; j < 4; j++) {
        const int n_g = bn * 128 + wc * 64 + j * 16 + l16;
        const int sec = n_g >> 10, e = n_g & 1023;
        const float* bias = (sec == 0) ? b0 : ((sec == 1) ? b1 : b2);
        const float be = bias[e];
        float v4[4];
#pragma unroll
        for (int r = 0; r < 4; r++) {
          float v = acc[i][j][r] + be;
          if (sec < 2) v = (v > 0.f) ? (v + 1.f) : __expf(v);
          v4[r] = v;
        }
        const int h = e >> 6, d = e & 63;
        const int bh = b * 16 + h;
        if (sec <= 1) {
          u16* dst = (sec == 0) ? q_o : k_o;
          const size_t tb = (((size_t)bh * 8192 + l0) << 6) + d;
#pragma unroll
          for (int r = 0; r < 4; r++) dst[tb + (size_t)r * 64] = f2bf(v4[r]);
        }
        if (sec >= 1) {
          u16* dstT = (sec == 1) ? kt_o : vt_o;
          u32x2 p;
          p.x = (u32)f2bf(v4[0]) | ((u32)f2bf(v4[1]) << 16);
          p.y = (u32)f2bf(v4[2]) | ((u32)f2bf(v4[3]) << 16);
          *(u32x2*)&dstT[(((size_t)(bh * 32 + nch)) * 64 + d) * 256 + c0] = p;
        }
      }
    }
  } else {
#pragma unroll
    for (int i = 0; i < 4; i++) {
#pragma unroll
      for (int j = 0; j < 4; j++) {
#pragma unroll
        for (int r = 0; r < 4; r++) {
          int m_g = bm * 128 + wr * 64 + i * 16 + quad * 4 + r;
          int n_g = bn * 128 + wc * 64 + j * 16 + l16;
          float v = acc[i][j][r] + b0[n_g] + xres[(size_t)m_g * 1024 + n_g];
          y_o[(size_t)m_g * 1024 + n_g] = v;
        }
      }
    }
  }
}

// ---------------- phase A: per-chunk S^T = v^T k ([d2][d1]) and z = colsum k ----------------
// Pure global-fragment MFMA: kt, vt are [chunk][d][c] bf16. No LDS.
__global__ __launch_bounds__(256) void phaseA_k(const u16* __restrict__ kt, const u16* __restrict__ vt,
                                                float* __restrict__ ST, float* __restrict__ zc) {
  const int tid = threadIdx.x;
  const int wave = tid >> 6, lane = tid & 63;
  const int quad = lane >> 4, l16 = lane & 15;
  const int wr = wave >> 1, wc = wave & 1;
  const int bhn = blockIdx.x;
  const u16* ktc = kt + (size_t)bhn * 16384;
  const u16* vtc = vt + (size_t)bhn * 16384;

  f32x4 zero = {0.f, 0.f, 0.f, 0.f};
  f32x4 t4[2][2];
  f32x4 za[2];
#pragma unroll
  for (int i = 0; i < 2; i++) {
    za[i] = zero;
#pragma unroll
    for (int j = 0; j < 2; j++) t4[i][j] = zero;
  }
  bf16x8 ones;
#pragma unroll
  for (int j = 0; j < 8; j++) ones[j] = (short)0x3F80;

#pragma unroll
  for (int ks = 0; ks < 8; ks++) {
    bf16x8 av[2], bk2[2];
#pragma unroll
    for (int t = 0; t < 2; t++) av[t] = *(const bf16x8*)&vtc[(wr * 32 + t * 16 + l16) * 256 + ks * 32 + quad * 8];
#pragma unroll
    for (int t = 0; t < 2; t++) bk2[t] = *(const bf16x8*)&ktc[(wc * 32 + t * 16 + l16) * 256 + ks * 32 + quad * 8];
#pragma unroll
    for (int i = 0; i < 2; i++)
#pragma unroll
      for (int j = 0; j < 2; j++) t4[i][j] = MFMA16(av[i], bk2[j], t4[i][j]);
    if (wr == 0) {
#pragma unroll
      for (int j = 0; j < 2; j++) za[j] = MFMA16(ones, bk2[j], za[j]);
    }
  }
  float* Sg = ST + (size_t)bhn * 4096;
#pragma unroll
  for (int i = 0; i < 2; i++)
#pragma unroll
    for (int j = 0; j < 2; j++)
#pragma unroll
      for (int r = 0; r < 4; r++)
        Sg[(wr * 32 + i * 16 + quad * 4 + r) * 64 + wc * 32 + j * 16 + l16] = t4[i][j][r];
  if (wr == 0 && quad == 0) {
#pragma unroll
    for (int j = 0; j < 2; j++) zc[(size_t)bhn * 64 + wc * 32 + j * 16 + l16] = za[j][0];
  }
}

// ---------------- phase B: exclusive prefix over chunks (one scan lane per thread) ----------------
__global__ __launch_bounds__(256) void phaseB_k(const float* __restrict__ ST, const float* __restrict__ zc,
                                                u16* __restrict__ STp, u16* __restrict__ zp) {
  const int blk = blockIdx.x, tid = threadIdx.x;
  if (blk < 512) {
    const int bh = blk >> 4;
    const int e = ((blk & 15) << 8) + tid;
    const size_t base = (size_t)bh * 32 * 4096 + e;
    float run = 0.f;
#pragma unroll
    for (int n = 0; n < 32; n++) {
      float v = ST[base + (size_t)n * 4096];
      STp[base + (size_t)n * 4096] = f2bf(run);
      run += v;
    }
  } else {
    const int idx = (blk - 512) * 256 + tid;  // 0..2047
    const int bh = idx >> 6, d = idx & 63;
    const size_t zb = (size_t)bh * 2048 + d;
    float run = 0.f;
#pragma unroll
    for (int n = 0; n < 32; n++) {
      float v = zc[zb + n * 64];
      zp[zb + n * 64] = f2bf(run);
      run += v;
    }
  }
}

// ---------------- phase C: per-chunk output ----------------
// LDS only for P (wave-private -> no __syncthreads anywhere). v^T read from global vt.
__global__ __launch_bounds__(256, 2) void phaseC_k(const u16* __restrict__ qb, const u16* __restrict__ kb,
                                                   const u16* __restrict__ vt, const u16* __restrict__ STp,
                                                   const u16* __restrict__ zp, u16* __restrict__ ao) {
  __shared__ u16 P[4][64 * 72];
  const int tid = threadIdx.x;
  const int wave = tid >> 6, lane = tid & 63;
  const int quad = lane >> 4, l16 = lane & 15;
  const int bhn = blockIdx.x;
  const int bh = bhn >> 5, n = bhn & 31;
  const int b = bh >> 4, h = bh & 15;
  const size_t cbase = (size_t)bhn * 16384;
  const u16* qc = qb + cbase;
  const u16* kc = kb + cbase;
  const u16* vtc = vt + cbase;
  const u16* STg = STp + (size_t)bhn * 4096;
  const u16* zg = zp + (size_t)bhn * 64;

  f32x4 zero = {0.f, 0.f, 0.f, 0.f};
  f32x4 num[4][4];
  f32x4 den[4];
#pragma unroll
  for (int i = 0; i < 4; i++) {
    den[i] = zero;
#pragma unroll
    for (int j = 0; j < 4; j++) num[i][j] = zero;
  }
  bf16x8 ones;
#pragma unroll
  for (int j = 0; j < 8; j++) ones[j] = (short)0x3F80;

  // preload q fragments for this wave's 64-row band
  bf16x8 aq[4][2];
#pragma unroll
  for (int i = 0; i < 4; i++)
#pragma unroll
    for (int ks = 0; ks < 2; ks++)
      aq[i][ks] = *(const bf16x8*)&qc[(wave * 64 + i * 16 + l16) * 64 + ks * 32 + quad * 8];

  // num += q @ S_prefix ; den += q . z_prefix (z replicated across B cols)
#pragma unroll
  for (int ks = 0; ks < 2; ks++) {
    bf16x8 bz = *(const bf16x8*)&zg[ks * 32 + quad * 8];
    bf16x8 bs[4];
#pragma unroll
    for (int j = 0; j < 4; j++) bs[j] = *(const bf16x8*)&STg[(j * 16 + l16) * 64 + ks * 32 + quad * 8];
#pragma unroll
    for (int i = 0; i < 4; i++) {
      den[i] = MFMA16(aq[i][ks], bz, den[i]);
#pragma unroll
      for (int j = 0; j < 4; j++) num[i][j] = MFMA16(aq[i][ks], bs[j], num[i][j]);
    }
  }

  u16* Pw = &P[wave][0];

  for (int cc = 0; cc <= wave; cc++) {  // slabs with cc > wave are fully masked
    // scores = q k^T for this 64-col slab, mask, write P (bf16, wave-private)
    bf16x8 bkf[2][4];
#pragma unroll
    for (int ks = 0; ks < 2; ks++)
#pragma unroll
      for (int j = 0; j < 4; j++)
        bkf[ks][j] = *(const bf16x8*)&kc[(cc * 64 + j * 16 + l16) * 64 + ks * 32 + quad * 8];
#pragma unroll
    for (int i = 0; i < 4; i++) {
      f32x4 sc4[4];
#pragma unroll
      for (int j = 0; j < 4; j++) sc4[j] = zero;
#pragma unroll
      for (int ks = 0; ks < 2; ks++)
#pragma unroll
        for (int j = 0; j < 4; j++) sc4[j] = MFMA16(aq[i][ks], bkf[ks][j], sc4[j]);
#pragma unroll
      for (int j = 0; j < 4; j++) {
#pragma unroll
        for (int r = 0; r < 4; r++) {
          int row = wave * 64 + i * 16 + quad * 4 + r;
          int col = cc * 64 + j * 16 + l16;
          float v = (col <= row) ? sc4[j][r] : 0.f;
          Pw[(i * 16 + quad * 4 + r) * 72 + j * 16 + l16] = f2bf(v);
        }
      }
    }
    // num += P @ v ; den += rowsum(P) via ones fragment (v^T direct from global)
    bf16x8 bvf[2][4];
#pragma unroll
    for (int ks2 = 0; ks2 < 2; ks2++)
#pragma unroll
      for (int j = 0; j < 4; j++)
        bvf[ks2][j] = *(const bf16x8*)&vtc[(j * 16 + l16) * 256 + cc * 64 + ks2 * 32 + quad * 8];
#pragma unroll
    for (int i = 0; i < 4; i++) {
#pragma unroll
      for (int ks2 = 0; ks2 < 2; ks2++) {
        bf16x8 ap = *(const bf16x8*)&Pw[(i * 16 + l16) * 72 + ks2 * 32 + quad * 8];
#pragma unroll
        for (int j = 0; j < 4; j++) num[i][j] = MFMA16(ap, bvf[ks2][j], num[i][j]);
        den[i] = MFMA16(ap, ones, den[i]);
      }
    }
  }

  // epilogue: divide and scatter to attnout [B,L,H,D] bf16
#pragma unroll
  for (int i = 0; i < 4; i++)
#pragma unroll
    for (int j = 0; j < 4; j++)
#pragma unroll
      for (int r = 0; r < 4; r++) {
        int row = wave * 64 + i * 16 + quad * 4 + r;
        int col = j * 16 + l16;
        float o = num[i][j][r] / (den[i][r] + 1e-6f);
        int l = n * 256 + row;
        ao[(((size_t)b * 8192 + l) * 16 + h) * 64 + col] = f2bf(o);
      }
}

// ---------------- LayerNorm ----------------
__global__ __launch_bounds__(256) void ln_k(const float* __restrict__ y, const float* __restrict__ gamma,
                                            const float* __restrict__ beta, float* __restrict__ o) {
  int row = blockIdx.x, tid = threadIdx.x;
  const float4* yv = (const float4*)(y + (size_t)row * 1024);
  float4 v = yv[tid];
  float s = v.x + v.y + v.z + v.w;
  float s2 = v.x * v.x + v.y * v.y + v.z * v.z + v.w * v.w;
#pragma unroll
  for (int off = 32; off; off >>= 1) {
    s += __shfl_down(s, off, 64);
    s2 += __shfl_down(s2, off, 64);
  }
  __shared__ float red[8];
  int wave = tid >> 6, lane = tid & 63;
  if (lane == 0) { red[wave] = s; red[4 + wave] = s2; }
  __syncthreads();
  s = red[0] + red[1] + red[2] + red[3];
  s2 = red[4] + red[5] + red[6] + red[7];
  float mu = s * 0.0009765625f;
  float var = s2 * 0.0009765625f - mu * mu;
  float inv = rsqrtf(var + 1e-5f);
  float4 g = ((const float4*)gamma)[tid];
  float4 bb = ((const float4*)beta)[tid];
  float4 ov;
  ov.x = g.x * (v.x - mu) * inv + bb.x;
  ov.y = g.y * (v.y - mu) * inv + bb.y;
  ov.z = g.z * (v.z - mu) * inv + bb.z;
  ov.w = g.w * (v.w - mu) * inv + bb.w;
  ((float4*)(o + (size_t)row * 1024))[tid] = ov;
}

extern "C" void kernel_launch(void* const* d_in, const int* in_sizes, int n_in,
                              void* d_out, int out_size, void* d_ws, size_t ws_size,
                              hipStream_t stream) {
  const float* x = (const float*)d_in[0];
  const float* Wq = (const float*)d_in[1];
  const float* bq = (const float*)d_in[2];
  const float* Wk = (const float*)d_in[3];
  const float* bk = (const float*)d_in[4];
  const float* Wv = (const float*)d_in[5];
  const float* bv = (const float*)d_in[6];
  const float* Wo = (const float*)d_in[7];
  const float* bo = (const float*)d_in[8];
  const float* gamma = (const float*)d_in[9];
  const float* beta = (const float*)d_in[10];

  char* ws = (char*)d_ws;
  u16* xb = (u16*)(ws + 0);                  // 33554432 B (dead after gemm0)
  u16* qb = (u16*)(ws + 33554432);           // 33554432 B (dead after phaseC)
  u16* kb = (u16*)(ws + 67108864);           // 33554432 B (dead after phaseC)
  u16* kt = (u16*)(ws + 100663296);          // 33554432 B (dead after phaseA)
  u16* vt = (u16*)(ws + 134217728);          // 33554432 B (dead after phaseC)
  u16* wqkvT = (u16*)(ws + 167772160);       // 6291456 B
  u16* woT = (u16*)(ws + 174063616);         // 2097152 B
  float* SchT = (float*)(ws + 176160768);    // 16777216 B
  float* zch = (float*)(ws + 192937984);     // 262144 B
  u16* STp = (u16*)(ws + 193200128);         // 8388608 B
  u16* zp = (u16*)(ws + 201588736);          // 131072 B -> end 201719808
  u16* attno = kt;                           // reuse kt region (dead after phaseA)
  float* ypre = (float*)(ws + 0);            // 67108864 B over xb+qb (dead by then)

  cast_k<<<4096, 256, 0, stream>>>(x, xb);
  wT_k<<<dim3(32, 32, 4), 256, 0, stream>>>(Wq, Wk, Wv, Wo, wqkvT, woT);
  gemm_k<0><<<dim3(24, 128), 256, 0, stream>>>(xb, wqkvT, bq, bk, bv, qb, kb, kt, vt, nullptr, nullptr);
  phaseA_k<<<1024, 256, 0, stream>>>(kt, vt, SchT, zch);
  phaseB_k<<<520, 256, 0, stream>>>(SchT, zch, STp, zp);
  phaseC_k<<<1024, 256, 0, stream>>>(qb, kb, vt, STp, zp, attno);
  gemm_k<1><<<dim3(8, 128), 256, 0, stream>>>(attno, woT, bo, nullptr, nullptr, nullptr, nullptr, nullptr, nullptr,
                                              x, ypre);
  ln_k<<<16384, 256, 0, stream>>>(ypre, gamma, beta, (float*)d_out);
}

// Round 4
// 389.365 us; speedup vs baseline: 1.1575x; 1.1271x over previous
//
#include <hip/hip_runtime.h>
#include <stdint.h>

typedef __attribute__((ext_vector_type(8))) short bf16x8;
typedef __attribute__((ext_vector_type(4))) float f32x4;
typedef __attribute__((ext_vector_type(2))) unsigned int u32x2;
typedef unsigned short u16;
typedef unsigned int u32;

#define MFMA16(a, b, c) __builtin_amdgcn_mfma_f32_16x16x32_bf16((a), (b), (c), 0, 0, 0)

__device__ __forceinline__ u16 f2bf(float f) {
  union { float f; u32 u; } c; c.f = f;
  u32 u = c.u;
  return (u16)((u + 0x7FFFu + ((u >> 16) & 1u)) >> 16);
}

__device__ __forceinline__ float bf2f(u16 h) {
  union { u32 u; float f; } c;
  c.u = ((u32)h) << 16;
  return c.f;
}

__device__ __forceinline__ void gll16(const void* g, void* l) {
  __builtin_amdgcn_global_load_lds((__attribute__((address_space(1))) void*)(g),
                                   (__attribute__((address_space(3))) void*)(l),
                                   16, 0, 0);
}

// ---------------- prep: cast x to bf16 ----------------
__global__ __launch_bounds__(256) void cast_k(const float* __restrict__ x, u16* __restrict__ xb) {
  int idx = blockIdx.x * 256 + threadIdx.x;
#pragma unroll
  for (int it = 0; it < 4; it++) {
    size_t i = (size_t)idx + (size_t)it * 1048576;
    float4 v = ((const float4*)x)[i];
    u32x2 p;
    p.x = (u32)f2bf(v.x) | ((u32)f2bf(v.y) << 16);
    p.y = (u32)f2bf(v.z) | ((u32)f2bf(v.w) << 16);
    ((u32x2*)xb)[i] = p;
  }
}

// ---------------- prep: weight transpose to [N][K] bf16 ----------------
__global__ __launch_bounds__(256) void wT_k(const float* __restrict__ Wq, const float* __restrict__ Wk,
                                            const float* __restrict__ Wv, const float* __restrict__ Wo,
                                            u16* __restrict__ wqkvT, u16* __restrict__ woT) {
  __shared__ float t[32][33];
  int which = blockIdx.z;
  const float* W = (which == 0) ? Wq : (which == 1) ? Wk : (which == 2) ? Wv : Wo;
  int k0 = blockIdx.y * 32, n0 = blockIdx.x * 32;
  int c = threadIdx.x & 31, r8 = threadIdx.x >> 5;
#pragma unroll
  for (int rr = 0; rr < 32; rr += 8)
    t[r8 + rr][c] = W[(size_t)(k0 + r8 + rr) * 1024 + n0 + c];
  __syncthreads();
  u16* outp = (which < 3) ? (wqkvT + (size_t)which * 1048576) : woT;
#pragma unroll
  for (int rr = 0; rr < 32; rr += 8)
    outp[(size_t)(n0 + r8 + rr) * 1024 + k0 + c] = f2bf(t[c][r8 + rr]);
}

// ---------------- GEMM (m97 structure, BK=64 double-staged): C = A[M,K] * Bt[N,K]^T ----------------
// MODE 0: QKV (N=3072): bias + phi(q,k); writes q,k natural [B,H,L,D]; v transposed
//         [B,H,N,D,C] (8B packed stores).
// MODE 1: OUT (N=1024): + bo + bf16 residual, write bf16 ypre
template <int MODE>
__global__ __launch_bounds__(256, 2) void gemm_k(
    const u16* __restrict__ A, const u16* __restrict__ Bt,
    const float* __restrict__ b0, const float* __restrict__ b1, const float* __restrict__ b2,
    u16* __restrict__ q_o, u16* __restrict__ k_o, u16* __restrict__ vt_o,
    const u16* __restrict__ xres, u16* __restrict__ y_o) {
  __shared__ u16 As[2][4096];
  __shared__ u16 Bs[2][4096];
  const int tid = threadIdx.x;
  const int wave = tid >> 6, lane = tid & 63;
  const int quad = lane >> 4, l16 = lane & 15;
  const int wr = wave >> 1, wc = wave & 1;
  const int bm = blockIdx.x, bn = blockIdx.y;  // bm fastest: same-bm blocks share XCD (id % 8)

  const int r_a = wave * 32 + (lane >> 2);
  const int c_a = (lane & 3) * 8;
  const size_t arow = (size_t)bm * 128;
  const size_t brow = (size_t)bn * 128;

  f32x4 zero = {0.f, 0.f, 0.f, 0.f};
  f32x4 acc[4][4];
#pragma unroll
  for (int i = 0; i < 4; i++)
#pragma unroll
    for (int j = 0; j < 4; j++) acc[i][j] = zero;

  for (int k0 = 0; k0 < 1024; k0 += 64) {
#pragma unroll
    for (int h = 0; h < 2; h++) {
      const int kk = k0 + h * 32;
#pragma unroll
      for (int jc = 0; jc < 2; jc++) {
        int r = r_a + jc * 16;
        int lo = wave * 1024 + jc * 512 + lane * 8;
        gll16(A + (arow + r) * 1024 + kk + c_a, &As[h][lo]);
        gll16(Bt + (brow + r) * 1024 + kk + c_a, &Bs[h][lo]);
      }
    }
    __syncthreads();
#pragma unroll
    for (int h = 0; h < 2; h++) {
      bf16x8 af[4], bf[4];
#pragma unroll
      for (int t = 0; t < 4; t++) af[t] = *(const bf16x8*)&As[h][(wr * 64 + t * 16 + l16) * 32 + quad * 8];
#pragma unroll
      for (int t = 0; t < 4; t++) bf[t] = *(const bf16x8*)&Bs[h][(wc * 64 + t * 16 + l16) * 32 + quad * 8];
#pragma unroll
      for (int i = 0; i < 4; i++)
#pragma unroll
        for (int j = 0; j < 4; j++) acc[i][j] = MFMA16(af[i], bf[j], acc[i][j]);
    }
    __syncthreads();
  }

  if (MODE == 0) {
#pragma unroll
    for (int i = 0; i < 4; i++) {
      const int m0 = bm * 128 + wr * 64 + i * 16 + quad * 4;  // 4 consecutive tokens
      const int b = m0 >> 13, l0 = m0 & 8191;
      const int nch = l0 >> 8, c0 = l0 & 255;
#pragma unroll
      for (int j = 0; j < 4; j++) {
        const int n_g = bn * 128 + wc * 64 + j * 16 + l16;
        const int sec = n_g >> 10, e = n_g & 1023;
        const float* bias = (sec == 0) ? b0 : ((sec == 1) ? b1 : b2);
        const float be = bias[e];
        float v4[4];
#pragma unroll
        for (int r = 0; r < 4; r++) {
          float v = acc[i][j][r] + be;
          if (sec < 2) v = (v > 0.f) ? (v + 1.f) : __expf(v);
          v4[r] = v;
        }
        const int h = e >> 6, d = e & 63;
        const int bh = b * 16 + h;
        if (sec == 2) {
          u32x2 p;
          p.x = (u32)f2bf(v4[0]) | ((u32)f2bf(v4[1]) << 16);
          p.y = (u32)f2bf(v4[2]) | ((u32)f2bf(v4[3]) << 16);
          *(u32x2*)&vt_o[(((size_t)(bh * 32 + nch)) * 64 + d) * 256 + c0] = p;
        } else {
          u16* dst = (sec == 0) ? q_o : k_o;
          const size_t tb = (((size_t)bh * 8192 + l0) << 6) + d;
#pragma unroll
          for (int r = 0; r < 4; r++) dst[tb + (size_t)r * 64] = f2bf(v4[r]);
        }
      }
    }
  } else {
#pragma unroll
    for (int i = 0; i < 4; i++) {
#pragma unroll
      for (int j = 0; j < 4; j++) {
#pragma unroll
        for (int r = 0; r < 4; r++) {
          int m_g = bm * 128 + wr * 64 + i * 16 + quad * 4 + r;
          int n_g = bn * 128 + wc * 64 + j * 16 + l16;
          float v = acc[i][j][r] + b0[n_g] + bf2f(xres[(size_t)m_g * 1024 + n_g]);
          y_o[(size_t)m_g * 1024 + n_g] = f2bf(v);
        }
      }
    }
  }
}

// ---------------- phase A: per-chunk S^T = v^T k ([d2][d1]) and z = colsum k ----------------
// A-operand (v^T) from global vt; B-operand (k^T) via LDS transpose of k natural.
// Transpose store mapping: per-instruction d is wave-uniform -> banks = c/2 -> 2-way (free).
__global__ __launch_bounds__(256, 2) void phaseA_k(const u16* __restrict__ kb, const u16* __restrict__ vt,
                                                   float* __restrict__ ST, float* __restrict__ zc) {
  __shared__ u16 kT[64 * 264];  // stride 264: rows 16B-aligned, b128 bank-spread (132 % 32 == 4)
  const int tid = threadIdx.x;
  const int wave = tid >> 6, lane = tid & 63;
  const int quad = lane >> 4, l16 = lane & 15;
  const int wr = wave >> 1, wc = wave & 1;
  const int bhn = blockIdx.x;
  const u16* kc = kb + (size_t)bhn * 16384;   // natural [c][d]
  const u16* vtc = vt + (size_t)bhn * 16384;  // transposed [d][c]

  // stage k^T: wave handles dblk {wave, wave+4}; lanes span c (conflict-free scalar writes)
#pragma unroll
  for (int t = 0; t < 2; t++) {
    const int dblk = wave + 4 * t;
#pragma unroll
    for (int itc = 0; itc < 4; itc++) {
      const int c = itc * 64 + lane;
      bf16x8 kv = *(const bf16x8*)&kc[c * 64 + dblk * 8];
#pragma unroll
      for (int j = 0; j < 8; j++) kT[(dblk * 8 + j) * 264 + c] = (u16)kv[j];
    }
  }
  __syncthreads();

  f32x4 zero = {0.f, 0.f, 0.f, 0.f};
  f32x4 t4[2][2];
  f32x4 za[2];
#pragma unroll
  for (int i = 0; i < 2; i++) {
    za[i] = zero;
#pragma unroll
    for (int j = 0; j < 2; j++) t4[i][j] = zero;
  }
  bf16x8 ones;
#pragma unroll
  for (int j = 0; j < 8; j++) ones[j] = (short)0x3F80;

#pragma unroll
  for (int ks = 0; ks < 8; ks++) {
    bf16x8 av[2], bk2[2];
#pragma unroll
    for (int t = 0; t < 2; t++) av[t] = *(const bf16x8*)&vtc[(wr * 32 + t * 16 + l16) * 256 + ks * 32 + quad * 8];
#pragma unroll
    for (int t = 0; t < 2; t++) bk2[t] = *(const bf16x8*)&kT[(wc * 32 + t * 16 + l16) * 264 + ks * 32 + quad * 8];
#pragma unroll
    for (int i = 0; i < 2; i++)
#pragma unroll
      for (int j = 0; j < 2; j++) t4[i][j] = MFMA16(av[i], bk2[j], t4[i][j]);
    if (wr == 0) {
#pragma unroll
      for (int j = 0; j < 2; j++) za[j] = MFMA16(ones, bk2[j], za[j]);
    }
  }
  float* Sg = ST + (size_t)bhn * 4096;
#pragma unroll
  for (int i = 0; i < 2; i++)
#pragma unroll
    for (int j = 0; j < 2; j++)
#pragma unroll
      for (int r = 0; r < 4; r++)
        Sg[(wr * 32 + i * 16 + quad * 4 + r) * 64 + wc * 32 + j * 16 + l16] = t4[i][j][r];
  if (wr == 0 && quad == 0) {
#pragma unroll
    for (int j = 0; j < 2; j++) zc[(size_t)bhn * 64 + wc * 32 + j * 16 + l16] = za[j][0];
  }
}

// ---------------- phase B: exclusive prefix over chunks (one scan lane per thread) ----------------
__global__ __launch_bounds__(256) void phaseB_k(const float* __restrict__ ST, const float* __restrict__ zc,
                                                u16* __restrict__ STp, u16* __restrict__ zp) {
  const int blk = blockIdx.x, tid = threadIdx.x;
  if (blk < 512) {
    const int bh = blk >> 4;
    const int e = ((blk & 15) << 8) + tid;
    const size_t base = (size_t)bh * 32 * 4096 + e;
    float run = 0.f;
#pragma unroll
    for (int n = 0; n < 32; n++) {
      float v = ST[base + (size_t)n * 4096];
      STp[base + (size_t)n * 4096] = f2bf(run);
      run += v;
    }
  } else {
    const int idx = (blk - 512) * 256 + tid;  // 0..2047
    const int bh = idx >> 6, d = idx & 63;
    const size_t zb = (size_t)bh * 2048 + d;
    float run = 0.f;
#pragma unroll
    for (int n = 0; n < 32; n++) {
      float v = zc[zb + n * 64];
      zp[zb + n * 64] = f2bf(run);
      run += v;
    }
  }
}

// ---------------- phase C: per-chunk output ----------------
// LDS only for P (wave-private -> no __syncthreads anywhere). v^T read from global vt.
__global__ __launch_bounds__(256, 2) void phaseC_k(const u16* __restrict__ qb, const u16* __restrict__ kb,
                                                   const u16* __restrict__ vt, const u16* __restrict__ STp,
                                                   const u16* __restrict__ zp, u16* __restrict__ ao) {
  __shared__ u16 P[4][64 * 72];
  const int tid = threadIdx.x;
  const int wave = tid >> 6, lane = tid & 63;
  const int quad = lane >> 4, l16 = lane & 15;
  const int bhn = blockIdx.x;
  const int bh = bhn >> 5, n = bhn & 31;
  const int b = bh >> 4, h = bh & 15;
  const size_t cbase = (size_t)bhn * 16384;
  const u16* qc = qb + cbase;
  const u16* kc = kb + cbase;
  const u16* vtc = vt + cbase;
  const u16* STg = STp + (size_t)bhn * 4096;
  const u16* zg = zp + (size_t)bhn * 64;

  f32x4 zero = {0.f, 0.f, 0.f, 0.f};
  f32x4 num[4][4];
  f32x4 den[4];
#pragma unroll
  for (int i = 0; i < 4; i++) {
    den[i] = zero;
#pragma unroll
    for (int j = 0; j < 4; j++) num[i][j] = zero;
  }
  bf16x8 ones;
#pragma unroll
  for (int j = 0; j < 8; j++) ones[j] = (short)0x3F80;

  // preload q fragments for this wave's 64-row band
  bf16x8 aq[4][2];
#pragma unroll
  for (int i = 0; i < 4; i++)
#pragma unroll
    for (int ks = 0; ks < 2; ks++)
      aq[i][ks] = *(const bf16x8*)&qc[(wave * 64 + i * 16 + l16) * 64 + ks * 32 + quad * 8];

  // num += q @ S_prefix ; den += q . z_prefix (z replicated across B cols)
#pragma unroll
  for (int ks = 0; ks < 2; ks++) {
    bf16x8 bz = *(const bf16x8*)&zg[ks * 32 + quad * 8];
    bf16x8 bs[4];
#pragma unroll
    for (int j = 0; j < 4; j++) bs[j] = *(const bf16x8*)&STg[(j * 16 + l16) * 64 + ks * 32 + quad * 8];
#pragma unroll
    for (int i = 0; i < 4; i++) {
      den[i] = MFMA16(aq[i][ks], bz, den[i]);
#pragma unroll
      for (int j = 0; j < 4; j++) num[i][j] = MFMA16(aq[i][ks], bs[j], num[i][j]);
    }
  }

  u16* Pw = &P[wave][0];

  for (int cc = 0; cc <= wave; cc++) {  // slabs with cc > wave are fully masked
    // scores = q k^T for this 64-col slab, mask, write P (bf16, wave-private)
    bf16x8 bkf[2][4];
#pragma unroll
    for (int ks = 0; ks < 2; ks++)
#pragma unroll
      for (int j = 0; j < 4; j++)
        bkf[ks][j] = *(const bf16x8*)&kc[(cc * 64 + j * 16 + l16) * 64 + ks * 32 + quad * 8];
#pragma unroll
    for (int i = 0; i < 4; i++) {
      f32x4 sc4[4];
#pragma unroll
      for (int j = 0; j < 4; j++) sc4[j] = zero;
#pragma unroll
      for (int ks = 0; ks < 2; ks++)
#pragma unroll
        for (int j = 0; j < 4; j++) sc4[j] = MFMA16(aq[i][ks], bkf[ks][j], sc4[j]);
#pragma unroll
      for (int j = 0; j < 4; j++) {
#pragma unroll
        for (int r = 0; r < 4; r++) {
          int row = wave * 64 + i * 16 + quad * 4 + r;
          int col = cc * 64 + j * 16 + l16;
          float v = (col <= row) ? sc4[j][r] : 0.f;
          Pw[(i * 16 + quad * 4 + r) * 72 + j * 16 + l16] = f2bf(v);
        }
      }
    }
    // num += P @ v ; den += rowsum(P) via ones fragment (v^T direct from global)
    bf16x8 bvf[2][4];
#pragma unroll
    for (int ks2 = 0; ks2 < 2; ks2++)
#pragma unroll
      for (int j = 0; j < 4; j++)
        bvf[ks2][j] = *(const bf16x8*)&vtc[(j * 16 + l16) * 256 + cc * 64 + ks2 * 32 + quad * 8];
#pragma unroll
    for (int i = 0; i < 4; i++) {
#pragma unroll
      for (int ks2 = 0; ks2 < 2; ks2++) {
        bf16x8 ap = *(const bf16x8*)&Pw[(i * 16 + l16) * 72 + ks2 * 32 + quad * 8];
#pragma unroll
        for (int j = 0; j < 4; j++) num[i][j] = MFMA16(ap, bvf[ks2][j], num[i][j]);
        den[i] = MFMA16(ap, ones, den[i]);
      }
    }
  }

  // epilogue: divide and scatter to attnout [B,L,H,D] bf16
#pragma unroll
  for (int i = 0; i < 4; i++)
#pragma unroll
    for (int j = 0; j < 4; j++)
#pragma unroll
      for (int r = 0; r < 4; r++) {
        int row = wave * 64 + i * 16 + quad * 4 + r;
        int col = j * 16 + l16;
        float o = num[i][j][r] / (den[i][r] + 1e-6f);
        int l = n * 256 + row;
        ao[(((size_t)b * 8192 + l) * 16 + h) * 64 + col] = f2bf(o);
      }
}

// ---------------- LayerNorm (bf16 in, f32 out) ----------------
__global__ __launch_bounds__(256) void ln_k(const u16* __restrict__ y, const float* __restrict__ gamma,
                                            const float* __restrict__ beta, float* __restrict__ o) {
  int row = blockIdx.x, tid = threadIdx.x;
  u32x2 pv = ((const u32x2*)(y + (size_t)row * 1024))[tid];
  float vx = bf2f((u16)(pv.x & 0xFFFF)), vy = bf2f((u16)(pv.x >> 16));
  float vz = bf2f((u16)(pv.y & 0xFFFF)), vw = bf2f((u16)(pv.y >> 16));
  float s = vx + vy + vz + vw;
  float s2 = vx * vx + vy * vy + vz * vz + vw * vw;
#pragma unroll
  for (int off = 32; off; off >>= 1) {
    s += __shfl_down(s, off, 64);
    s2 += __shfl_down(s2, off, 64);
  }
  __shared__ float red[8];
  int wave = tid >> 6, lane = tid & 63;
  if (lane == 0) { red[wave] = s; red[4 + wave] = s2; }
  __syncthreads();
  s = red[0] + red[1] + red[2] + red[3];
  s2 = red[4] + red[5] + red[6] + red[7];
  float mu = s * 0.0009765625f;
  float var = s2 * 0.0009765625f - mu * mu;
  float inv = rsqrtf(var + 1e-5f);
  float4 g = ((const float4*)gamma)[tid];
  float4 bb = ((const float4*)beta)[tid];
  float4 ov;
  ov.x = g.x * (vx - mu) * inv + bb.x;
  ov.y = g.y * (vy - mu) * inv + bb.y;
  ov.z = g.z * (vz - mu) * inv + bb.z;
  ov.w = g.w * (vw - mu) * inv + bb.w;
  ((float4*)(o + (size_t)row * 1024))[tid] = ov;
}

extern "C" void kernel_launch(void* const* d_in, const int* in_sizes, int n_in,
                              void* d_out, int out_size, void* d_ws, size_t ws_size,
                              hipStream_t stream) {
  const float* x = (const float*)d_in[0];
  const float* Wq = (const float*)d_in[1];
  const float* bq = (const float*)d_in[2];
  const float* Wk = (const float*)d_in[3];
  const float* bk = (const float*)d_in[4];
  const float* Wv = (const float*)d_in[5];
  const float* bv = (const float*)d_in[6];
  const float* Wo = (const float*)d_in[7];
  const float* bo = (const float*)d_in[8];
  const float* gamma = (const float*)d_in[9];
  const float* beta = (const float*)d_in[10];

  char* ws = (char*)d_ws;
  u16* xb = (u16*)(ws + 0);                  // 33 MB (alive through gemm1: residual)
  u16* qb = (u16*)(ws + 33554432);           // 33 MB (dead after phaseC)
  u16* kb = (u16*)(ws + 67108864);           // 33 MB (dead after phaseC)
  u16* attno = (u16*)(ws + 100663296);       // 33 MB (phaseC out, gemm1 in)
  u16* vt = (u16*)(ws + 134217728);          // 33 MB (dead after phaseC)
  u16* wqkvT = (u16*)(ws + 167772160);       // 6 MB
  u16* woT = (u16*)(ws + 174063616);         // 2 MB
  float* SchT = (float*)(ws + 176160768);    // 16 MB
  float* zch = (float*)(ws + 192937984);     // 256 KB
  u16* STp = (u16*)(ws + 193200128);         // 8 MB
  u16* zp = (u16*)(ws + 201588736);          // 128 KB -> end 201719808
  u16* ypre = qb;                            // bf16 33 MB over qb (dead after phaseC)

  cast_k<<<4096, 256, 0, stream>>>(x, xb);
  wT_k<<<dim3(32, 32, 4), 256, 0, stream>>>(Wq, Wk, Wv, Wo, wqkvT, woT);
  gemm_k<0><<<dim3(128, 24), 256, 0, stream>>>(xb, wqkvT, bq, bk, bv, qb, kb, vt, nullptr, nullptr);
  phaseA_k<<<1024, 256, 0, stream>>>(kb, vt, SchT, zch);
  phaseB_k<<<520, 256, 0, stream>>>(SchT, zch, STp, zp);
  phaseC_k<<<1024, 256, 0, stream>>>(qb, kb, vt, STp, zp, attno);
  gemm_k<1><<<dim3(128, 8), 256, 0, stream>>>(attno, woT, bo, nullptr, nullptr, nullptr, nullptr, nullptr, xb,
                                              ypre);
  ln_k<<<16384, 256, 0, stream>>>(ypre, gamma, beta, (float*)d_out);
}